// Round 9
// baseline (180.466 us; speedup 1.0000x reference)
//
#include <hip/hip_runtime.h>
#include <hip/hip_bf16.h>

#define F_DIM 128
#define C_DIM 100000
#define B_ROWS 512
#define ANGLE 0.5f
#define CPB 128            // classes per block
#define NCB 782            // ceil(100000/128); last block has 96 OOB pad classes
#define OOB_PAD 96.0f      // pad classes contribute exp2(0)=1 each to row sums

typedef __attribute__((ext_vector_type(4))) float  f32x4;
typedef __attribute__((ext_vector_type(8))) short  bf16x8;

// packed f32x2 -> bf16x2 (v_cvt_pk_bf16_f32 on gfx950); low = a, high = b
static __device__ __forceinline__ unsigned int pk2(float a, float b) {
    __hip_bfloat162 h = __float22bfloat162_rn(float2{a, b});
    return *(unsigned int*)&h;
}

#if __has_builtin(__builtin_amdgcn_exp2f)
#define EXP2(x) __builtin_amdgcn_exp2f(x)
#else
#define EXP2(x) exp2f(x)
#endif

// ---------------------------------------------------------------------------
// arc_prep: feat_bf = bf16(log2e * feat). 65536 elements, 8 per thread.
// ---------------------------------------------------------------------------
__global__ __launch_bounds__(256)
void arc_prep(const float* __restrict__ feat, unsigned short* __restrict__ fbf)
{
    const int i = (blockIdx.x * 256 + threadIdx.x) * 8;
    const float s = 1.4426950408889634f;   // log2(e)
    const f32x4 a = *(const f32x4*)(feat + i);
    const f32x4 b = *(const f32x4*)(feat + i + 4);
    union { bf16x8 h; unsigned int u[4]; } fr;
    fr.u[0] = pk2(a[0] * s, a[1] * s);
    fr.u[1] = pk2(a[2] * s, a[3] * s);
    fr.u[2] = pk2(b[0] * s, b[1] * s);
    fr.u[3] = pk2(b[2] * s, b[3] * s);
    *(bf16x8*)&fbf[i] = fr.h;
}

// ---------------------------------------------------------------------------
// arc_main: block = 4 waves = 128 classes x 128 batch rows. grid (782, 4).
//   Per wave: 32 rows (fB[2][4], no spill), 64 MFMA, 64 exp2, 32 ds_read_b128.
//   LDS 32 KB -> 5 resident blocks/CU (20 waves, ~62% occ); 4-wave barriers
//   are fine-grained so independent blocks' stage/compute phases interleave.
//   Staging uses packed cvt; feat pre-converted (cvt-free fragment loads).
// ---------------------------------------------------------------------------
__global__ __launch_bounds__(256, 4)
void arc_main(const unsigned short* __restrict__ fbf,
              const float* __restrict__ w,
              float* __restrict__ pp)        // [NCB][512]
{
    __shared__ unsigned short lBt[128 * 128];   // [c][k] swizzled, 32 KB

    const int tid = threadIdx.x;
    const int cb  = blockIdx.x;
    const int c0  = cb * CPB;
    const int r0  = blockIdx.y * 128;

    // ---- Phase 1: stage w^T. thread (c, g) covers k = g*64 .. g*64+63 ----
    {
        const int c  = tid & 127;
        const int g  = tid >> 7;              // 0..1
        const int gc = c0 + c;
        #pragma unroll
        for (int j = 0; j < 8; ++j) {
            float v[8];
            #pragma unroll
            for (int i = 0; i < 8; ++i) {
                const int k = g * 64 + j * 8 + i;
                v[i] = (gc < C_DIM) ? w[(size_t)k * C_DIM + gc] : 0.f;
            }
            union { bf16x8 h; unsigned int u[4]; } fr;
            fr.u[0] = pk2(v[0], v[1]); fr.u[1] = pk2(v[2], v[3]);
            fr.u[2] = pk2(v[4], v[5]); fr.u[3] = pk2(v[6], v[7]);
            const int pc = (g * 8 + j) ^ (c & 15);   // 16B-chunk XOR swizzle
            *(bf16x8*)&lBt[c * 128 + pc * 8] = fr.h;
        }
    }

    const int lane = tid & 63;
    const int wv   = tid >> 6;                // 0..3 -> 32-batch strip
    const int quad = lane >> 4;
    const int l15  = lane & 15;

    // ---- Phase 2: feat fragments, direct bf16 loads (issued pre-barrier) ----
    bf16x8 fB[2][4];
    #pragma unroll
    for (int s = 0; s < 2; ++s) {
        const unsigned short* fr =
            fbf + (size_t)(r0 + wv * 32 + s * 16 + l15) * F_DIM + quad * 8;
        #pragma unroll
        for (int ks = 0; ks < 4; ++ks)
            fB[s][ks] = *(const bf16x8*)(fr + ks * 32);
    }
    __syncthreads();

    // ---- Phase 3: m-loop: 4 ds_read_b128 -> 8 MFMA -> 8 exp2 ----
    float eA0 = 0.f, eA1 = 0.f, eA2 = 0.f, eA3 = 0.f;
    float eB0 = 0.f, eB1 = 0.f, eB2 = 0.f, eB3 = 0.f;
    #pragma unroll
    for (int m = 0; m < 8; ++m) {
        const int row = m * 16 + l15;         // class row
        f32x4 a0 = {0.f, 0.f, 0.f, 0.f};
        f32x4 a1 = {0.f, 0.f, 0.f, 0.f};
        #pragma unroll
        for (int ks = 0; ks < 4; ++ks) {
            const int pc = (ks * 4 + quad) ^ (row & 15);
            const bf16x8 af = *(const bf16x8*)&lBt[row * 128 + pc * 8];
            a0 = __builtin_amdgcn_mfma_f32_16x16x32_bf16(af, fB[0][ks], a0, 0, 0, 0);
            a1 = __builtin_amdgcn_mfma_f32_16x16x32_bf16(af, fB[1][ks], a1, 0, 0, 0);
        }
        eA0 += EXP2(a0[0]); eA1 += EXP2(a0[1]);
        eA2 += EXP2(a0[2]); eA3 += EXP2(a0[3]);
        eB0 += EXP2(a1[0]); eB1 += EXP2(a1[1]);
        eB2 += EXP2(a1[2]); eB3 += EXP2(a1[3]);
    }

    float esum0 = (eA0 + eA1) + (eA2 + eA3);
    float esum1 = (eB0 + eB1) + (eB2 + eB3);
    esum0 += __shfl_xor(esum0, 16); esum0 += __shfl_xor(esum0, 32);
    esum1 += __shfl_xor(esum1, 16); esum1 += __shfl_xor(esum1, 32);
    if (lane < 16) {
        pp[(size_t)cb * 512 + r0 + wv * 32 + lane]      = esum0;
        pp[(size_t)cb * 512 + r0 + wv * 32 + 16 + lane] = esum1;
    }
}

// ---------------------------------------------------------------------------
// arc_row: exact fp32 target-column terms + partial reduce. One wave per row.
// ---------------------------------------------------------------------------
__global__ void arc_row(const float* __restrict__ feat,
                        const float* __restrict__ w,
                        const int*   __restrict__ target,
                        const float* __restrict__ pp,
                        float* __restrict__ term)
{
    const int b    = blockIdx.x;
    const int lane = threadIdx.x;             // 64
    const int t    = target[b];

    float dot = 0.f, wsq = 0.f, fsq = 0.f, rs = 0.f;
    #pragma unroll
    for (int h = 0; h < 2; ++h) {
        const int f  = lane + h * 64;
        const float fv = feat[b * F_DIM + f];
        const float wv = w[(size_t)f * C_DIM + t];
        dot += fv * wv;
        wsq += wv * wv;
        fsq += fv * fv;
    }
    for (int j = lane; j < NCB; j += 64)
        rs += pp[(size_t)j * 512 + b];

    #pragma unroll
    for (int off = 32; off > 0; off >>= 1) {
        dot += __shfl_xor(dot, off);
        wsq += __shfl_xor(wsq, off);
        fsq += __shfl_xor(fsq, off);
        rs  += __shfl_xor(rs,  off);
    }
    if (lane == 0) {
        const float mod = sqrtf(fsq) * sqrtf(wsq);
        float ct = dot / (mod * 1.01f);
        ct = fminf(1.f, fmaxf(-1.f, ct));
        const float th   = acosf(ct) + ANGLE;
        const float marg = mod * cosf(th);
        const float down = rs - OOB_PAD - expf(dot) + expf(marg);
        term[b] = marg - logf(down);
    }
}

// ---------------------------------------------------------------------------
__global__ void arc_loss(const float* __restrict__ term,
                         float* __restrict__ out)
{
    __shared__ float red[B_ROWS];
    const int b = threadIdx.x;
    red[b] = term[b];
    __syncthreads();
    #pragma unroll
    for (int st = 256; st > 0; st >>= 1) {
        if (b < st) red[b] += red[b + st];
        __syncthreads();
    }
    if (b == 0) out[0] = -red[0] / (float)B_ROWS;
}

// ---------------------------------------------------------------------------
extern "C" void kernel_launch(void* const* d_in, const int* in_sizes, int n_in,
                              void* d_out, int out_size, void* d_ws, size_t ws_size,
                              hipStream_t stream)
{
    const float* feat   = (const float*)d_in[0];   // [512,128] fp32
    const float* w      = (const float*)d_in[1];   // [128,100000] fp32
    const int*   target = (const int*)d_in[2];     // [512]

    unsigned short* fbf = (unsigned short*)d_ws;          // [512][128] bf16, prescaled
    float* pp   = (float*)(fbf + (size_t)B_ROWS * F_DIM); // [782][512]
    float* term = pp + (size_t)NCB * 512;                 // [512]

    arc_prep<<<32, 256, 0, stream>>>(feat, fbf);
    arc_main<<<dim3(NCB, 4), 256, 0, stream>>>(fbf, w, pp);
    arc_row <<<B_ROWS, 64, 0, stream>>>(feat, w, target, pp, term);
    arc_loss<<<1, B_ROWS, 0, stream>>>(term, (float*)d_out);
}

// Round 10
// 137.420 us; speedup vs baseline: 1.3132x; 1.3132x over previous
//
#include <hip/hip_runtime.h>
#include <hip/hip_bf16.h>

#define F_DIM 128
#define C_DIM 100000
#define B_ROWS 512
#define ANGLE 0.5f
#define CPB 128            // classes per arc_main block / per w_t tile
#define NCB 782            // 782*128 = 100096 padded classes
#define OOB_PAD 96.0f      // pad classes contribute exp2(0)=1 each to row sums
#define NTRB 1564          // transpose blocks (64 classes each)

typedef __attribute__((ext_vector_type(4))) float  f32x4;
typedef __attribute__((ext_vector_type(8))) short  bf16x8;

// packed f32x2 -> bf16x2 (v_cvt_pk_bf16_f32); low = a, high = b
static __device__ __forceinline__ unsigned int pk2(float a, float b) {
    __hip_bfloat162 h = __float22bfloat162_rn(float2{a, b});
    return *(unsigned int*)&h;
}

#if __has_builtin(__builtin_amdgcn_exp2f)
#define EXP2(x) __builtin_amdgcn_exp2f(x)
#else
#define EXP2(x) exp2f(x)
#endif

// async global->LDS, 16 B per lane (global_load_lds_dwordx4)
static __device__ __forceinline__ void gld16(const void* g, void* l) {
    __builtin_amdgcn_global_load_lds(
        (const __attribute__((address_space(1))) unsigned int*)g,
        (__attribute__((address_space(3))) unsigned int*)l, 16, 0, 0);
}

// ---------------------------------------------------------------------------
// arc_tr: blocks 0..1563: w [k][c] fp32 -> w_t bf16, tile-major:
//   tile t (128 classes), row r = c&127 at t*32768 + r*256 bytes, 16B chunk j
//   stored at position pc = j ^ (r&15)  (XOR swizzle baked into global layout).
//   Reads coalesced (256B/inst); LDS pivot (pad 65); writes full 64B lines.
// blocks 1564..1595: arc_prep: fbf = bf16(log2e * feat).
// ---------------------------------------------------------------------------
__global__ __launch_bounds__(256)
void arc_tr(const float* __restrict__ w, const float* __restrict__ feat,
            unsigned short* __restrict__ w_t, unsigned short* __restrict__ fbf)
{
    const int bx  = blockIdx.x;
    const int tid = threadIdx.x;

    if (bx >= NTRB) {   // ---- prep part ----
        const int i = ((bx - NTRB) * 256 + tid) * 8;
        const float s = 1.4426950408889634f;   // log2(e)
        const f32x4 a = *(const f32x4*)(feat + i);
        const f32x4 b = *(const f32x4*)(feat + i + 4);
        union { bf16x8 h; unsigned int u[4]; } fr;
        fr.u[0] = pk2(a[0] * s, a[1] * s);
        fr.u[1] = pk2(a[2] * s, a[3] * s);
        fr.u[2] = pk2(b[0] * s, b[1] * s);
        fr.u[3] = pk2(b[2] * s, b[3] * s);
        *(bf16x8*)&fbf[i] = fr.h;
        return;
    }

    // ---- transpose part: 64 classes x 128 k ----
    __shared__ float sT[128 * 65];             // [k][c], pad 65
    const int c0 = bx * 64;
    const int cl = tid & 63;
    const int wq = tid >> 6;                   // 0..3
    const int c  = c0 + cl;
    const bool cv = (c < C_DIM);

    #pragma unroll
    for (int p = 0; p < 32; ++p) {
        const int k = p * 4 + wq;
        sT[k * 65 + cl] = cv ? w[(size_t)k * C_DIM + c] : 0.f;
    }
    __syncthreads();

    // write out: thread -> row rl = tid>>2, chunk group jg = tid&3 (4 chunks)
    const int rl = tid >> 2;
    const int jg = tid & 3;
    const int gc = c0 + rl;
    const int t  = gc >> 7;
    const int r  = gc & 127;
    unsigned short* base = w_t + (size_t)t * 16384 + r * 128;   // u16 units
    #pragma unroll
    for (int jj = 0; jj < 4; ++jj) {
        const int j  = jg * 4 + jj;            // k-chunk 0..15
        const int pc = j ^ (r & 15);
        float v[8];
        #pragma unroll
        for (int i = 0; i < 8; ++i)
            v[i] = sT[(8 * j + i) * 65 + rl];
        union { bf16x8 h; unsigned int u[4]; } fr;
        fr.u[0] = pk2(v[0], v[1]); fr.u[1] = pk2(v[2], v[3]);
        fr.u[2] = pk2(v[4], v[5]); fr.u[3] = pk2(v[6], v[7]);
        *(bf16x8*)(base + pc * 8) = fr.h;
    }
}

// ---------------------------------------------------------------------------
// arc_main: block = 4 waves = 128 classes x 128 batch rows. grid (782, 4).
//   Staging = 8x global_load_lds_dwordx4 per thread: contiguous 32 KB tile of
//   pre-swizzled w_t -> LDS. Zero staging VALU, zero staging VGPRs. Then the
//   R5-proven conflict-free ds_read_b128 / MFMA / exp2 loop. LDS 32 KB ->
//   up to 5 resident blocks/CU; async staging overlaps other blocks' compute.
// ---------------------------------------------------------------------------
__global__ __launch_bounds__(256, 4)
void arc_main(const unsigned short* __restrict__ fbf,
              const unsigned short* __restrict__ w_t,
              float* __restrict__ pp)        // [NCB][512]
{
    __shared__ unsigned short lBt[128 * 128];   // pre-swizzled tile, 32 KB

    const int tid = threadIdx.x;
    const int cb  = blockIdx.x;
    const int r0  = blockIdx.y * 128;

    // ---- async stage: contiguous 32 KB, 8 insts/thread ----
    {
        const char* gsrc = (const char*)(w_t + (size_t)cb * 16384) + tid * 16;
        char*       ldst = (char*)lBt + tid * 16;
        #pragma unroll
        for (int it = 0; it < 8; ++it)
            gld16(gsrc + it * 4096, ldst + it * 4096);
    }

    const int lane = tid & 63;
    const int wv   = tid >> 6;                // 0..3 -> 32-batch strip
    const int quad = lane >> 4;
    const int l15  = lane & 15;

    // ---- feat fragments, direct bf16 loads (overlap the DMA) ----
    bf16x8 fB[2][4];
    #pragma unroll
    for (int s = 0; s < 2; ++s) {
        const unsigned short* fr =
            fbf + (size_t)(r0 + wv * 32 + s * 16 + l15) * F_DIM + quad * 8;
        #pragma unroll
        for (int ks = 0; ks < 4; ++ks)
            fB[s][ks] = *(const bf16x8*)(fr + ks * 32);
    }
    __syncthreads();

    // ---- m-loop: 4 ds_read_b128 -> 8 MFMA -> 8 exp2 ----
    float eA0 = 0.f, eA1 = 0.f, eA2 = 0.f, eA3 = 0.f;
    float eB0 = 0.f, eB1 = 0.f, eB2 = 0.f, eB3 = 0.f;
    #pragma unroll
    for (int m = 0; m < 8; ++m) {
        const int row = m * 16 + l15;         // class row
        f32x4 a0 = {0.f, 0.f, 0.f, 0.f};
        f32x4 a1 = {0.f, 0.f, 0.f, 0.f};
        #pragma unroll
        for (int ks = 0; ks < 4; ++ks) {
            const int pc = (ks * 4 + quad) ^ (row & 15);
            const bf16x8 af = *(const bf16x8*)&lBt[row * 128 + pc * 8];
            a0 = __builtin_amdgcn_mfma_f32_16x16x32_bf16(af, fB[0][ks], a0, 0, 0, 0);
            a1 = __builtin_amdgcn_mfma_f32_16x16x32_bf16(af, fB[1][ks], a1, 0, 0, 0);
        }
        eA0 += EXP2(a0[0]); eA1 += EXP2(a0[1]);
        eA2 += EXP2(a0[2]); eA3 += EXP2(a0[3]);
        eB0 += EXP2(a1[0]); eB1 += EXP2(a1[1]);
        eB2 += EXP2(a1[2]); eB3 += EXP2(a1[3]);
    }

    float esum0 = (eA0 + eA1) + (eA2 + eA3);
    float esum1 = (eB0 + eB1) + (eB2 + eB3);
    esum0 += __shfl_xor(esum0, 16); esum0 += __shfl_xor(esum0, 32);
    esum1 += __shfl_xor(esum1, 16); esum1 += __shfl_xor(esum1, 32);
    if (lane < 16) {
        pp[(size_t)cb * 512 + r0 + wv * 32 + lane]      = esum0;
        pp[(size_t)cb * 512 + r0 + wv * 32 + 16 + lane] = esum1;
    }
}

// ---------------------------------------------------------------------------
// arc_row: exact fp32 target-column terms + partial reduce. One wave per row.
// ---------------------------------------------------------------------------
__global__ void arc_row(const float* __restrict__ feat,
                        const float* __restrict__ w,
                        const int*   __restrict__ target,
                        const float* __restrict__ pp,
                        float* __restrict__ term)
{
    const int b    = blockIdx.x;
    const int lane = threadIdx.x;             // 64
    const int t    = target[b];

    float dot = 0.f, wsq = 0.f, fsq = 0.f, rs = 0.f;
    #pragma unroll
    for (int h = 0; h < 2; ++h) {
        const int f  = lane + h * 64;
        const float fv = feat[b * F_DIM + f];
        const float wv = w[(size_t)f * C_DIM + t];
        dot += fv * wv;
        wsq += wv * wv;
        fsq += fv * fv;
    }
    for (int j = lane; j < NCB; j += 64)
        rs += pp[(size_t)j * 512 + b];

    #pragma unroll
    for (int off = 32; off > 0; off >>= 1) {
        dot += __shfl_xor(dot, off);
        wsq += __shfl_xor(wsq, off);
        fsq += __shfl_xor(fsq, off);
        rs  += __shfl_xor(rs,  off);
    }
    if (lane == 0) {
        const float mod = sqrtf(fsq) * sqrtf(wsq);
        float ct = dot / (mod * 1.01f);
        ct = fminf(1.f, fmaxf(-1.f, ct));
        const float th   = acosf(ct) + ANGLE;
        const float marg = mod * cosf(th);
        const float down = rs - OOB_PAD - expf(dot) + expf(marg);
        term[b] = marg - logf(down);
    }
}

// ---------------------------------------------------------------------------
__global__ void arc_loss(const float* __restrict__ term,
                         float* __restrict__ out)
{
    __shared__ float red[B_ROWS];
    const int b = threadIdx.x;
    red[b] = term[b];
    __syncthreads();
    #pragma unroll
    for (int st = 256; st > 0; st >>= 1) {
        if (b < st) red[b] += red[b + st];
        __syncthreads();
    }
    if (b == 0) out[0] = -red[0] / (float)B_ROWS;
}

// ---------------------------------------------------------------------------
extern "C" void kernel_launch(void* const* d_in, const int* in_sizes, int n_in,
                              void* d_out, int out_size, void* d_ws, size_t ws_size,
                              hipStream_t stream)
{
    const float* feat   = (const float*)d_in[0];   // [512,128] fp32
    const float* w      = (const float*)d_in[1];   // [128,100000] fp32
    const int*   target = (const int*)d_in[2];     // [512]

    unsigned short* w_t = (unsigned short*)d_ws;             // [782 tiles][128][128] bf16
    unsigned short* fbf = w_t + (size_t)NCB * 16384;         // [512][128] bf16 prescaled
    float* pp   = (float*)(fbf + (size_t)B_ROWS * F_DIM);    // [782][512]
    float* term = pp + (size_t)NCB * 512;                    // [512]

    arc_tr  <<<NTRB + 32, 256, 0, stream>>>(w, feat, w_t, fbf);
    arc_main<<<dim3(NCB, 4), 256, 0, stream>>>(fbf, w_t, pp);
    arc_row <<<B_ROWS, 64, 0, stream>>>(feat, w, target, pp, term);
    arc_loss<<<1, B_ROWS, 0, stream>>>(term, (float*)d_out);
}